// Round 8
// baseline (352.070 us; speedup 1.0000x reference)
//
#include <hip/hip_runtime.h>
#include <math.h>

#define SEQ 1024
#define NTOK 4096
#define DM 512
#define FF 2048
#define NE 8

typedef __attribute__((ext_vector_type(8))) short bf16x8;
typedef __attribute__((ext_vector_type(4))) float f32x4;

__device__ __forceinline__ short f2bf(float f) {
  unsigned u = __float_as_uint(f);
  unsigned r = (u + 0x7FFFu + ((u >> 16) & 1u)) >> 16;
  return (short)r;
}
__device__ __forceinline__ float bf2f(short h) {
  return __uint_as_float(((unsigned)(unsigned short)h) << 16);
}

#define GLOAD_LDS16(g, l) __builtin_amdgcn_global_load_lds( \
    (const __attribute__((address_space(1))) void*)(g),     \
    (__attribute__((address_space(3))) void*)(l), 16, 0, 0)

// ---------- fused split of x, in_proj_w, out_proj_w -> (hi,lo) bf16 planes ----------
__global__ __launch_bounds__(256) void split3_kernel(
    const float* __restrict__ x, short* __restrict__ xh, short* __restrict__ xl,
    const float* __restrict__ w1, short* __restrict__ w1h, short* __restrict__ w1l,
    const float* __restrict__ w2, short* __restrict__ w2h, short* __restrict__ w2l) {
  const int bid = blockIdx.x;
  const float* src; short* hi; short* lo; size_t off;
  if (bid < 1024)      { src = x;  hi = xh;  lo = xl;  off = (size_t)bid * 2048; }
  else if (bid < 1408) { src = w1; hi = w1h; lo = w1l; off = (size_t)(bid - 1024) * 2048; }
  else                 { src = w2; hi = w2h; lo = w2l; off = (size_t)(bid - 1408) * 2048; }
  const size_t base = off + threadIdx.x * 8;
  float4 v0 = *reinterpret_cast<const float4*>(src + base);
  float4 v1 = *reinterpret_cast<const float4*>(src + base + 4);
  short h[8]; short l[8];
  float v[8] = {v0.x, v0.y, v0.z, v0.w, v1.x, v1.y, v1.z, v1.w};
#pragma unroll
  for (int i = 0; i < 8; ++i) {
    h[i] = f2bf(v[i]);
    l[i] = f2bf(v[i] - bf2f(h[i]));
  }
  *reinterpret_cast<short4*>(hi + base)     = make_short4(h[0], h[1], h[2], h[3]);
  *reinterpret_cast<short4*>(hi + base + 4) = make_short4(h[4], h[5], h[6], h[7]);
  *reinterpret_cast<short4*>(lo + base)     = make_short4(l[0], l[1], l[2], l[3]);
  *reinterpret_cast<short4*>(lo + base + 4) = make_short4(l[4], l[5], l[6], l[7]);
}

// ---------- split-bf16 MFMA GEMM, BM=64 BN=64, double-buffered staging ----------
// C = A@B^T + bias + resid
__global__ __launch_bounds__(256) void gemm_split_db(const short* __restrict__ Ah, const short* __restrict__ Al,
    const short* __restrict__ Bh, const short* __restrict__ Bl,
    const float* __restrict__ bias, const float* __restrict__ resid, float* __restrict__ C,
    int N, int K) {
  __shared__ __align__(16) short AsH[2][2048], AsL[2][2048], BsH[2][2048], BsL[2][2048];
  const int n0 = blockIdx.x * 64, m0 = blockIdx.y * 64;
  const int tid = threadIdx.x;
  const int lane = tid & 63, w = tid >> 6;
  const int quad = lane >> 4, l15 = lane & 15;
  const int wm = (w & 1) * 32, wn = (w >> 1) * 32;
  const int sr = tid >> 2, sc = (tid & 3) * 8;
  const short* Ahp = Ah + (size_t)(m0 + sr) * K + sc;
  const short* Alp = Al + (size_t)(m0 + sr) * K + sc;
  const short* Bhp = Bh + (size_t)(n0 + sr) * K + sc;
  const short* Blp = Bl + (size_t)(n0 + sr) * K + sc;
  GLOAD_LDS16(Ahp, &AsH[0][tid * 8]);
  GLOAD_LDS16(Alp, &AsL[0][tid * 8]);
  GLOAD_LDS16(Bhp, &BsH[0][tid * 8]);
  GLOAD_LDS16(Blp, &BsL[0][tid * 8]);
  __syncthreads();
  f32x4 acc[2][2];
#pragma unroll
  for (int i = 0; i < 2; ++i)
#pragma unroll
    for (int j = 0; j < 2; ++j) acc[i][j] = (f32x4){0.f, 0.f, 0.f, 0.f};
  for (int kt = 0; kt < K; kt += 32) {
    const int cur = (kt >> 5) & 1;
    if (kt + 32 < K) {
      const int nxt = cur ^ 1;
      GLOAD_LDS16(Ahp + kt + 32, &AsH[nxt][tid * 8]);
      GLOAD_LDS16(Alp + kt + 32, &AsL[nxt][tid * 8]);
      GLOAD_LDS16(Bhp + kt + 32, &BsH[nxt][tid * 8]);
      GLOAD_LDS16(Blp + kt + 32, &BsL[nxt][tid * 8]);
    }
    bf16x8 ah[2], al[2], bh[2], bl[2];
#pragma unroll
    for (int i = 0; i < 2; ++i) {
      ah[i] = *reinterpret_cast<const bf16x8*>(&AsH[cur][(wm + i * 16 + l15) * 32 + quad * 8]);
      al[i] = *reinterpret_cast<const bf16x8*>(&AsL[cur][(wm + i * 16 + l15) * 32 + quad * 8]);
      bh[i] = *reinterpret_cast<const bf16x8*>(&BsH[cur][(wn + i * 16 + l15) * 32 + quad * 8]);
      bl[i] = *reinterpret_cast<const bf16x8*>(&BsL[cur][(wn + i * 16 + l15) * 32 + quad * 8]);
    }
#pragma unroll
    for (int i = 0; i < 2; ++i)
#pragma unroll
      for (int j = 0; j < 2; ++j) {
        acc[i][j] = __builtin_amdgcn_mfma_f32_16x16x32_bf16(al[i], bh[j], acc[i][j], 0, 0, 0);
        acc[i][j] = __builtin_amdgcn_mfma_f32_16x16x32_bf16(ah[i], bl[j], acc[i][j], 0, 0, 0);
        acc[i][j] = __builtin_amdgcn_mfma_f32_16x16x32_bf16(ah[i], bh[j], acc[i][j], 0, 0, 0);
      }
    __syncthreads();
  }
#pragma unroll
  for (int i = 0; i < 2; ++i) {
#pragma unroll
    for (int reg = 0; reg < 4; ++reg) {
      const int row = m0 + wm + i * 16 + quad * 4 + reg;
#pragma unroll
      for (int j = 0; j < 2; ++j) {
        const int col = n0 + wn + j * 16 + l15;
        float v = acc[i][j][reg] + bias[col] + resid[(size_t)row * N + col];
        C[(size_t)row * N + col] = v;
      }
    }
  }
}

// ---------- qkv GEMM: BM=64 BN=64, double-buffered, epilogue emits split planes ----------
__global__ __launch_bounds__(256) void gemm_split_qkv(const short* __restrict__ Ah, const short* __restrict__ Al,
    const short* __restrict__ Bh, const short* __restrict__ Bl, const float* __restrict__ bias,
    short* __restrict__ qkh, short* __restrict__ qkl, short* __restrict__ vh, short* __restrict__ vl) {
  const int K = DM;
  __shared__ __align__(16) short AsH[2][2048], AsL[2][2048], BsH[2][2048], BsL[2][2048];
  const int n0 = blockIdx.x * 64, m0 = blockIdx.y * 64;
  const int tid = threadIdx.x;
  const int lane = tid & 63, w = tid >> 6;
  const int quad = lane >> 4, l15 = lane & 15;
  const int wm = (w & 1) * 32, wn = (w >> 1) * 32;
  const int sr = tid >> 2, sc = (tid & 3) * 8;
  const short* Ahp = Ah + (size_t)(m0 + sr) * K + sc;
  const short* Alp = Al + (size_t)(m0 + sr) * K + sc;
  const short* Bhp = Bh + (size_t)(n0 + sr) * K + sc;
  const short* Blp = Bl + (size_t)(n0 + sr) * K + sc;
  GLOAD_LDS16(Ahp, &AsH[0][tid * 8]);
  GLOAD_LDS16(Alp, &AsL[0][tid * 8]);
  GLOAD_LDS16(Bhp, &BsH[0][tid * 8]);
  GLOAD_LDS16(Blp, &BsL[0][tid * 8]);
  __syncthreads();
  f32x4 acc[2][2];
#pragma unroll
  for (int i = 0; i < 2; ++i)
#pragma unroll
    for (int j = 0; j < 2; ++j) acc[i][j] = (f32x4){0.f, 0.f, 0.f, 0.f};
  for (int kt = 0; kt < K; kt += 32) {
    const int cur = (kt >> 5) & 1;
    if (kt + 32 < K) {
      const int nxt = cur ^ 1;
      GLOAD_LDS16(Ahp + kt + 32, &AsH[nxt][tid * 8]);
      GLOAD_LDS16(Alp + kt + 32, &AsL[nxt][tid * 8]);
      GLOAD_LDS16(Bhp + kt + 32, &BsH[nxt][tid * 8]);
      GLOAD_LDS16(Blp + kt + 32, &BsL[nxt][tid * 8]);
    }
    bf16x8 ah[2], al[2], bh[2], bl[2];
#pragma unroll
    for (int i = 0; i < 2; ++i) {
      ah[i] = *reinterpret_cast<const bf16x8*>(&AsH[cur][(wm + i * 16 + l15) * 32 + quad * 8]);
      al[i] = *reinterpret_cast<const bf16x8*>(&AsL[cur][(wm + i * 16 + l15) * 32 + quad * 8]);
      bh[i] = *reinterpret_cast<const bf16x8*>(&BsH[cur][(wn + i * 16 + l15) * 32 + quad * 8]);
      bl[i] = *reinterpret_cast<const bf16x8*>(&BsL[cur][(wn + i * 16 + l15) * 32 + quad * 8]);
    }
#pragma unroll
    for (int i = 0; i < 2; ++i)
#pragma unroll
      for (int j = 0; j < 2; ++j) {
        acc[i][j] = __builtin_amdgcn_mfma_f32_16x16x32_bf16(al[i], bh[j], acc[i][j], 0, 0, 0);
        acc[i][j] = __builtin_amdgcn_mfma_f32_16x16x32_bf16(ah[i], bl[j], acc[i][j], 0, 0, 0);
        acc[i][j] = __builtin_amdgcn_mfma_f32_16x16x32_bf16(ah[i], bh[j], acc[i][j], 0, 0, 0);
      }
    __syncthreads();
  }
  if (n0 < 1024) {
#pragma unroll
    for (int i = 0; i < 2; ++i) {
#pragma unroll
      for (int reg = 0; reg < 4; ++reg) {
        const int row = m0 + wm + i * 16 + quad * 4 + reg;
#pragma unroll
        for (int j = 0; j < 2; ++j) {
          const int col = n0 + wn + j * 16 + l15;
          float v = acc[i][j][reg] + bias[col];
          short hv = f2bf(v);
          size_t ad = (size_t)row * 1024 + col;
          qkh[ad] = hv;
          qkl[ad] = f2bf(v - bf2f(hv));
        }
      }
    }
  } else {
#pragma unroll
    for (int i = 0; i < 2; ++i) {
      const int row0 = m0 + wm + i * 16 + quad * 4;
      const int bb = row0 >> 10, s0 = row0 & 1023;
#pragma unroll
      for (int j = 0; j < 2; ++j) {
        const int col = n0 + wn + j * 16 + l15;
        const int c2 = col - 1024;
        const int hhd = c2 >> 6, d = c2 & 63;
        const float bc = bias[col];
        float v0 = acc[i][j][0] + bc, v1 = acc[i][j][1] + bc, v2 = acc[i][j][2] + bc, v3 = acc[i][j][3] + bc;
        short4 hv = make_short4(f2bf(v0), f2bf(v1), f2bf(v2), f2bf(v3));
        short4 lv = make_short4(f2bf(v0 - bf2f(hv.x)), f2bf(v1 - bf2f(hv.y)),
                                f2bf(v2 - bf2f(hv.z)), f2bf(v3 - bf2f(hv.w)));
        size_t ad = ((size_t)(bb * 8 + hhd) * 64 + d) * 1024 + s0;
        *reinterpret_cast<short4*>(vh + ad) = hv;
        *reinterpret_cast<short4*>(vl + ad) = lv;
      }
    }
  }
}

// ---------- MFMA flash attention, split-S over KV, Q in registers (32 KB LDS) ----------
__global__ __launch_bounds__(256) void attn_mfma(const short* __restrict__ qkh, const short* __restrict__ qkl,
    const short* __restrict__ vth, const short* __restrict__ vtl,
    float* __restrict__ opart, float* __restrict__ ml) {
  const int qt = blockIdx.x, hh = blockIdx.y;
  const int b = blockIdx.z >> 1, ks = blockIdx.z & 1;
  __shared__ __align__(16) short Kh[4096], Kl[4096], Vh[4096], Vl[4096];
  const int tid = threadIdx.x;
  const int lane = tid & 63, w = tid >> 6;
  const int quad = lane >> 4, l15 = lane & 15;
  const int tok0 = b * SEQ + qt * 64;
  const int srow = tid >> 2, schunk = (tid & 3) * 8;
  bf16x8 qfh[2], qfl[2];
  {
    const size_t qa = (size_t)(tok0 + w * 16 + l15) * 1024 + hh * 64 + quad * 8;
    qfh[0] = *reinterpret_cast<const bf16x8*>(qkh + qa);
    qfh[1] = *reinterpret_cast<const bf16x8*>(qkh + qa + 32);
    qfl[0] = *reinterpret_cast<const bf16x8*>(qkl + qa);
    qfl[1] = *reinterpret_cast<const bf16x8*>(qkl + qa + 32);
  }
  f32x4 oacc[4];
  float m_run[4], l_run[4];
#pragma unroll
  for (int r = 0; r < 4; ++r) { oacc[r] = (f32x4){0.f, 0.f, 0.f, 0.f}; m_run[r] = -1e30f; l_run[r] = 0.f; }
  const size_t kbase = (size_t)(b * SEQ) * 1024 + 512 + hh * 64;
  const size_t vbase = (size_t)(b * 8 + hh) * 64 * 1024;
  for (int kc = ks * 8; kc < ks * 8 + 8; ++kc) {
    const size_t ka = kbase + (size_t)(kc * 64 + srow) * 1024 + schunk;
    GLOAD_LDS16(qkh + ka,      &Kh[tid * 8]);
    GLOAD_LDS16(qkh + ka + 32, &Kh[2048 + tid * 8]);
    GLOAD_LDS16(qkl + ka,      &Kl[tid * 8]);
    GLOAD_LDS16(qkl + ka + 32, &Kl[2048 + tid * 8]);
    const size_t va = vbase + (size_t)srow * 1024 + kc * 64 + schunk;
    GLOAD_LDS16(vth + va,      &Vh[tid * 8]);
    GLOAD_LDS16(vth + va + 32, &Vh[2048 + tid * 8]);
    GLOAD_LDS16(vtl + va,      &Vl[tid * 8]);
    GLOAD_LDS16(vtl + va + 32, &Vl[2048 + tid * 8]);
    __syncthreads();
    f32x4 s[4];
#pragma unroll
    for (int j = 0; j < 4; ++j) s[j] = (f32x4){0.f, 0.f, 0.f, 0.f};
#pragma unroll
    for (int kk = 0; kk < 2; ++kk)
#pragma unroll
      for (int j = 0; j < 4; ++j) {
        bf16x8 kfh = *reinterpret_cast<const bf16x8*>(&Kh[kk * 2048 + (j * 16 + l15) * 32 + quad * 8]);
        bf16x8 kfl = *reinterpret_cast<const bf16x8*>(&Kl[kk * 2048 + (j * 16 + l15) * 32 + quad * 8]);
        s[j] = __builtin_amdgcn_mfma_f32_16x16x32_bf16(qfl[kk], kfh, s[j], 0, 0, 0);
        s[j] = __builtin_amdgcn_mfma_f32_16x16x32_bf16(qfh[kk], kfl, s[j], 0, 0, 0);
        s[j] = __builtin_amdgcn_mfma_f32_16x16x32_bf16(qfh[kk], kfh, s[j], 0, 0, 0);
      }
    __syncthreads();
    float pv[4][4], alpha[4];
#pragma unroll
    for (int reg = 0; reg < 4; ++reg) {
      float mc = fmaxf(fmaxf(s[0][reg], s[1][reg]), fmaxf(s[2][reg], s[3][reg]));
#pragma unroll
      for (int msk = 1; msk < 16; msk <<= 1) mc = fmaxf(mc, __shfl_xor(mc, msk, 64));
      mc *= 0.125f;
      float mn = fmaxf(m_run[reg], mc);
      alpha[reg] = expf(m_run[reg] - mn);
      m_run[reg] = mn;
      float pl = 0.f;
#pragma unroll
      for (int j = 0; j < 4; ++j) { float pp = expf(s[j][reg] * 0.125f - mn); pv[j][reg] = pp; pl += pp; }
#pragma unroll
      for (int msk = 1; msk < 16; msk <<= 1) pl += __shfl_xor(pl, msk, 64);
      l_run[reg] = l_run[reg] * alpha[reg] + pl;
    }
#pragma unroll
    for (int j = 0; j < 4; ++j) {
      oacc[j][0] *= alpha[0]; oacc[j][1] *= alpha[1]; oacc[j][2] *= alpha[2]; oacc[j][3] *= alpha[3];
    }
#pragma unroll
    for (int j = 0; j < 4; ++j) {
      const int cad = (j >> 1) * 2048 + (j & 1) * 16 + l15;
#pragma unroll
      for (int reg = 0; reg < 4; ++reg) {
        const int ad = cad + (w * 16 + quad * 4 + reg) * 32;
        float p = pv[j][reg];
        short hp = f2bf(p);
        Kh[ad] = hp;
        Kl[ad] = f2bf(p - bf2f(hp));
      }
    }
#pragma unroll
    for (int kk = 0; kk < 2; ++kk) {
      bf16x8 pfh = *reinterpret_cast<const bf16x8*>(&Kh[kk * 2048 + (w * 16 + l15) * 32 + quad * 8]);
      bf16x8 pfl = *reinterpret_cast<const bf16x8*>(&Kl[kk * 2048 + (w * 16 + l15) * 32 + quad * 8]);
#pragma unroll
      for (int j = 0; j < 4; ++j) {
        bf16x8 vfh = *reinterpret_cast<const bf16x8*>(&Vh[kk * 2048 + (j * 16 + l15) * 32 + quad * 8]);
        bf16x8 vfl = *reinterpret_cast<const bf16x8*>(&Vl[kk * 2048 + (j * 16 + l15) * 32 + quad * 8]);
        oacc[j] = __builtin_amdgcn_mfma_f32_16x16x32_bf16(pfl, vfh, oacc[j], 0, 0, 0);
        oacc[j] = __builtin_amdgcn_mfma_f32_16x16x32_bf16(pfh, vfl, oacc[j], 0, 0, 0);
        oacc[j] = __builtin_amdgcn_mfma_f32_16x16x32_bf16(pfh, vfh, oacc[j], 0, 0, 0);
      }
    }
    __syncthreads();
  }
  float* op = opart + (size_t)ks * 2097152;
#pragma unroll
  for (int reg = 0; reg < 4; ++reg) {
    const int rloc = w * 16 + quad * 4 + reg;
#pragma unroll
    for (int j = 0; j < 4; ++j)
      op[(size_t)(tok0 + rloc) * 512 + hh * 64 + j * 16 + l15] = oacc[j][reg];
    if (l15 == 0) {
      size_t mli = (((size_t)ks * 32 + b * 8 + hh) * 1024 + qt * 64 + rloc) * 2;
      ml[mli] = m_run[reg];
      ml[mli + 1] = l_run[reg];
    }
  }
}

// combine the two KV-half partials -> split attn_o planes
__global__ __launch_bounds__(64) void combine_attn(const float* __restrict__ opart, const float* __restrict__ ml,
    short* __restrict__ oh, short* __restrict__ ol) {
  const int t = blockIdx.x;
  const int b = t >> 10, s = t & 1023;
  const int tid = threadIdx.x;
#pragma unroll
  for (int hh = 0; hh < 8; ++hh) {
    size_t mli = (((size_t)(b * 8 + hh)) * 1024 + s) * 2;
    float m0 = ml[mli], l0 = ml[mli + 1];
    float m1 = ml[65536 + mli], l1 = ml[65536 + mli + 1];
    float mm = fmaxf(m0, m1);
    float a0 = expf(m0 - mm), a1 = expf(m1 - mm);
    float inv = 1.f / (l0 * a0 + l1 * a1);
    size_t ad = (size_t)t * 512 + hh * 64 + tid;
    float v = (opart[ad] * a0 + opart[2097152 + ad] * a1) * inv;
    short hv = f2bf(v);
    oh[ad] = hv;
    ol[ad] = f2bf(v - bf2f(hv));
  }
}

// ---------- fused LN1 + router logits + softmax + argmax ----------
__global__ __launch_bounds__(64) void ln_router(const float* __restrict__ r1,
    const float* __restrict__ g, const float* __restrict__ bta, const float* __restrict__ rw,
    float* __restrict__ h, float* __restrict__ rlog, float* __restrict__ probs, int* __restrict__ am) {
  const int t = blockIdx.x, tid = threadIdx.x;
  const size_t base = (size_t)t * DM + tid * 8;
  float4 v0 = *reinterpret_cast<const float4*>(r1 + base);
  float4 v1 = *reinterpret_cast<const float4*>(r1 + base + 4);
  float s = v0.x+v0.y+v0.z+v0.w + v1.x+v1.y+v1.z+v1.w;
  float q = v0.x*v0.x+v0.y*v0.y+v0.z*v0.z+v0.w*v0.w + v1.x*v1.x+v1.y*v1.y+v1.z*v1.z+v1.w*v1.w;
#pragma unroll
  for (int m = 1; m < 64; m <<= 1) { s += __shfl_xor(s, m, 64); q += __shfl_xor(q, m, 64); }
  float mean = s * (1.0f/512.0f);
  float var = q * (1.0f/512.0f) - mean * mean;
  float rs = rsqrtf(var + 1e-5f);
  float4 g0 = *reinterpret_cast<const float4*>(g + tid*8);
  float4 g1 = *reinterpret_cast<const float4*>(g + tid*8 + 4);
  float4 b0 = *reinterpret_cast<const float4*>(bta + tid*8);
  float4 b1 = *reinterpret_cast<const float4*>(bta + tid*8 + 4);
  float hv[8];
  hv[0] = (v0.x-mean)*rs*g0.x+b0.x; hv[1] = (v0.y-mean)*rs*g0.y+b0.y;
  hv[2] = (v0.z-mean)*rs*g0.z+b0.z; hv[3] = (v0.w-mean)*rs*g0.w+b0.w;
  hv[4] = (v1.x-mean)*rs*g1.x+b1.x; hv[5] = (v1.y-mean)*rs*g1.y+b1.y;
  hv[6] = (v1.z-mean)*rs*g1.z+b1.z; hv[7] = (v1.w-mean)*rs*g1.w+b1.w;
  *reinterpret_cast<float4*>(h + base)     = make_float4(hv[0], hv[1], hv[2], hv[3]);
  *reinterpret_cast<float4*>(h + base + 4) = make_float4(hv[4], hv[5], hv[6], hv[7]);
  float lg[8] = {0.f,0.f,0.f,0.f,0.f,0.f,0.f,0.f};
  const float* rwp = rw + tid * 64;
#pragma unroll
  for (int r = 0; r < 8; ++r) {
    float4 w0 = *reinterpret_cast<const float4*>(rwp + r * 8);
    float4 w1 = *reinterpret_cast<const float4*>(rwp + r * 8 + 4);
    float hr = hv[r];
    lg[0] += hr * w0.x; lg[1] += hr * w0.y; lg[2] += hr * w0.z; lg[3] += hr * w0.w;
    lg[4] += hr * w1.x; lg[5] += hr * w1.y; lg[6] += hr * w1.z; lg[7] += hr * w1.w;
  }
#pragma unroll
  for (int m = 1; m < 64; m <<= 1) {
#pragma unroll
    for (int e = 0; e < 8; ++e) lg[e] += __shfl_xor(lg[e], m, 64);
  }
  int best = 0; float bv = lg[0];
#pragma unroll
  for (int e = 1; e < 8; ++e) if (lg[e] > bv) { bv = lg[e]; best = e; }
  float se = 0.f;
#pragma unroll
  for (int e = 0; e < 8; ++e) se += expf(lg[e] - bv);
  float inv = 1.f / se;
  if (tid < 8) {
    rlog[t * 8 + tid] = lg[tid];
    probs[t * 8 + tid] = expf(lg[tid] - bv) * inv;
  }
  if (tid == 0) am[t] = best;
}

// LN2 with capacity-guarded MoE add
__global__ __launch_bounds__(64) void ln2_kernel(const float* __restrict__ x, const float* __restrict__ add,
    const int* __restrict__ pos, const int* __restrict__ capp,
    const float* __restrict__ g, const float* __restrict__ bta, float* __restrict__ y) {
  const int t = blockIdx.x, tid = threadIdx.x;
  const size_t base = (size_t)t * DM + tid * 8;
  float4 v0 = *reinterpret_cast<const float4*>(x + base);
  float4 v1 = *reinterpret_cast<const float4*>(x + base + 4);
  if (pos[t] <= *capp) {
    float4 a0 = *reinterpret_cast<const float4*>(add + base);
    float4 a1 = *reinterpret_cast<const float4*>(add + base + 4);
    v0.x += a0.x; v0.y += a0.y; v0.z += a0.z; v0.w += a0.w;
    v1.x += a1.x; v1.y += a1.y; v1.z += a1.z; v1.w += a1.w;
  }
  float s = v0.x+v0.y+v0.z+v0.w + v1.x+v1.y+v1.z+v1.w;
  float q = v0.x*v0.x+v0.y*v0.y+v0.z*v0.z+v0.w*v0.w + v1.x*v1.x+v1.y*v1.y+v1.z*v1.z+v1.w*v1.w;
#pragma unroll
  for (int m = 1; m < 64; m <<= 1) { s += __shfl_xor(s, m, 64); q += __shfl_xor(q, m, 64); }
  float mean = s * (1.0f/512.0f);
  float var = q * (1.0f/512.0f) - mean * mean;
  float rs = rsqrtf(var + 1e-5f);
  float4 g0 = *reinterpret_cast<const float4*>(g + tid*8);
  float4 g1 = *reinterpret_cast<const float4*>(g + tid*8 + 4);
  float4 b0 = *reinterpret_cast<const float4*>(bta + tid*8);
  float4 b1 = *reinterpret_cast<const float4*>(bta + tid*8 + 4);
  float4 o0 = make_float4((v0.x-mean)*rs*g0.x+b0.x, (v0.y-mean)*rs*g0.y+b0.y,
                          (v0.z-mean)*rs*g0.z+b0.z, (v0.w-mean)*rs*g0.w+b0.w);
  float4 o1 = make_float4((v1.x-mean)*rs*g1.x+b1.x, (v1.y-mean)*rs*g1.y+b1.y,
                          (v1.z-mean)*rs*g1.z+b1.z, (v1.w-mean)*rs*g1.w+b1.w);
  *reinterpret_cast<float4*>(y + base) = o0;
  *reinterpret_cast<float4*>(y + base + 4) = o1;
}

__global__ __launch_bounds__(256) void scan_kernel(const int* __restrict__ am, const float* __restrict__ probs,
    const int* __restrict__ capp, float* __restrict__ emask, int* __restrict__ pos, int* __restrict__ cnt) {
  const int bx = blockIdx.x;
  const int b = bx >> 3, e = bx & 7;
  const int tid = threadIdx.x;
  const int cap = *capp;
  __shared__ int arr[256];
  const int s_base = tid * 4;
  int f[4], incl[4];
  int c = 0;
#pragma unroll
  for (int i = 0; i < 4; ++i) {
    f[i] = (am[b * SEQ + s_base + i] == e) ? 1 : 0;
    c += f[i]; incl[i] = c;
  }
  arr[tid] = c;
  __syncthreads();
  for (int off = 1; off < 256; off <<= 1) {
    int v = (tid >= off) ? arr[tid - off] : 0;
    __syncthreads();
    arr[tid] += v;
    __syncthreads();
  }
  int excl = arr[tid] - c;
  int tot = arr[255];
#pragma unroll
  for (int i = 0; i < 4; ++i) {
    int token = b * SEQ + s_base + i;
    int p = excl + incl[i];
    bool kept = f[i] && (p <= cap);
    emask[(size_t)token * NE + e] = kept ? probs[token * NE + e] : 0.f;
    if (f[i]) pos[token] = p;
  }
  if (tid == 0) cnt[bx] = (tot < cap) ? tot : cap;
}

// ---------- fused weight transpose (wi + wo) ----------
__global__ __launch_bounds__(256) void transpose2_bf16(const float* __restrict__ wi, short* __restrict__ wi_t,
    const float* __restrict__ wo, short* __restrict__ wo_t) {
  __shared__ float T[32][33];
  const int z = blockIdx.z;
  const float* W; short* Wt; int K, N, k0, n0;
  if (z < 8) { W = wi + (size_t)z * DM * FF;      Wt = wi_t + (size_t)z * DM * FF;
               K = DM; N = FF; k0 = blockIdx.y * 32; n0 = blockIdx.x * 32; }
  else       { W = wo + (size_t)(z - 8) * FF * DM; Wt = wo_t + (size_t)(z - 8) * FF * DM;
               K = FF; N = DM; k0 = blockIdx.x * 32; n0 = blockIdx.y * 32; }
  const int r = threadIdx.x >> 3, c4 = (threadIdx.x & 7) * 4;
  float4 v = *reinterpret_cast<const float4*>(&W[(size_t)(k0 + r) * N + n0 + c4]);
  T[r][c4+0] = v.x; T[r][c4+1] = v.y; T[r][c4+2] = v.z; T[r][c4+3] = v.w;
  __syncthreads();
  short4 o;
  o.x = f2bf(T[c4+0][r]); o.y = f2bf(T[c4+1][r]); o.z = f2bf(T[c4+2][r]); o.w = f2bf(T[c4+3][r]);
  *reinterpret_cast<short4*>(&Wt[(size_t)(n0 + r) * K + k0 + c4]) = o;
}

// gather kept tokens (computes per-(b,e) offset from cnt inline)
__global__ __launch_bounds__(128) void gather_kernel(const float* __restrict__ h, const int* __restrict__ am,
    const int* __restrict__ pos, const int* __restrict__ capp, const int* __restrict__ cnt,
    const float* __restrict__ probs, short* __restrict__ Gb, int* __restrict__ tok, float* __restrict__ mscale) {
  const int t = blockIdx.x;
  const int b = t >> 10;
  const int e = am[t];
  const int p = pos[t];
  if (p > *capp) return;
  int off = 0;
  for (int b2 = 0; b2 < b; ++b2) off += cnt[b2 * 8 + e];
  const int slot = off + p - 1;
  const int idx = e * 1024 + slot;
  if (threadIdx.x == 0) { tok[idx] = t; mscale[idx] = probs[t * NE + e]; }
  float4 v = *reinterpret_cast<const float4*>(h + (size_t)t * DM + threadIdx.x * 4);
  short4 o; o.x = f2bf(v.x); o.y = f2bf(v.y); o.z = f2bf(v.z); o.w = f2bf(v.w);
  *reinterpret_cast<short4*>(Gb + (size_t)idx * DM + threadIdx.x * 4) = o;
}

// ---------- ffn1: BM=64 BN=128, double-buffered. 4 waves split N. ----------
__global__ __launch_bounds__(256) void ffn1_mfma(const short* __restrict__ Gb, const short* __restrict__ wi_t,
    short* __restrict__ mid, const int* __restrict__ cnt) {
  const int e = blockIdx.z;
  const int tot = cnt[e] + cnt[8 + e] + cnt[16 + e] + cnt[24 + e];
  const int m0 = blockIdx.y * 64;
  if (m0 >= tot) return;
  const int n0 = blockIdx.x * 128;
  __shared__ __align__(16) short As[2][2048];
  __shared__ __align__(16) short Bs[2][4096];
  const int tid = threadIdx.x;
  const int lane = tid & 63, w = tid >> 6;
  const int quad = lane >> 4, l15 = lane & 15;
  const int wn = w * 32;
  const int sr = tid >> 2, sc = (tid & 3) * 8;
  const short* Ap  = Gb + ((size_t)e * 1024 + m0 + sr) * DM + sc;
  const short* Bp  = wi_t + (size_t)e * FF * DM + (size_t)(n0 + sr) * DM + sc;
  const short* Bp2 = wi_t + (size_t)e * FF * DM + (size_t)(n0 + 64 + sr) * DM + sc;
  GLOAD_LDS16(Ap,  &As[0][tid * 8]);
  GLOAD_LDS16(Bp,  &Bs[0][tid * 8]);
  GLOAD_LDS16(Bp2, &Bs[0][2048 + tid * 8]);
  __syncthreads();
  f32x4 acc[4][2];
#pragma unroll
  for (int i = 0; i < 4; ++i)
#pragma unroll
    for (int j = 0; j < 2; ++j) acc[i][j] = (f32x4){0.f, 0.f, 0.f, 0.f};
  for (int kt = 0; kt < DM; kt += 32) {
    const int cur = (kt >> 5) & 1;
    if (kt + 32 < DM) {
      const int nxt = cur ^ 1;
      GLOAD_LDS16(Ap + kt + 32,  &As[nxt][tid * 8]);
      GLOAD_LDS16(Bp + kt + 32,  &Bs[nxt][tid * 8]);
      GLOAD_LDS16(Bp2 + kt + 32, &Bs[nxt][2048 + tid * 8]);
    }
    bf16x8 a[4], b[2];
#pragma unroll
    for (int i = 0; i < 4; ++i) a[i] = *reinterpret_cast<const bf16x8*>(&As[cur][(i * 16 + l15) * 32 + quad * 8]);
#pragma unroll
    for (int j = 0; j < 2; ++j) b[j] = *reinterpret_cast<const bf16x8*>(&Bs[cur][(wn + j * 16 + l15) * 32 + quad * 8]);
#pragma unroll
    for (int i = 0; i < 4; ++i)
#pragma unroll
      for (int j = 0; j < 2; ++j)
        acc[i][j] = __builtin_amdgcn_mfma_f32_16x16x32_bf16(a[i], b[j], acc[i][j], 0, 0, 0);
    __syncthreads();
  }
#pragma unroll
  for (int i = 0; i < 4; ++i) {
#pragma unroll
    for (int reg = 0; reg < 4; ++reg) {
      const int row = m0 + i * 16 + quad * 4 + reg;
      short* outr = mid + ((size_t)e * 1024 + row) * FF;
#pragma unroll
      for (int j = 0; j < 2; ++j) {
        float v = acc[i][j][reg];
        float gl = 0.5f * v * (1.f + erff(v * 0.70710678118654752f));
        outr[n0 + wn + j * 16 + l15] = f2bf(gl);
      }
    }
  }
}

// ---------- ffn2: BM=64 BN=64, double-buffered. ----------
__global__ __launch_bounds__(256) void ffn2_mfma(const short* __restrict__ mid, const short* __restrict__ wo_t,
    const int* __restrict__ tok, const float* __restrict__ mscale, const int* __restrict__ cnt,
    float* __restrict__ moebuf) {
  const int e = blockIdx.z;
  const int tot = cnt[e] + cnt[8 + e] + cnt[16 + e] + cnt[24 + e];
  const int m0 = blockIdx.y * 64;
  if (m0 >= tot) return;
  const int n0 = blockIdx.x * 64;
  __shared__ __align__(16) short As[2][2048];
  __shared__ __align__(16) short Bs[2][2048];
  const int tid = threadIdx.x;
  const int lane = tid & 63, w = tid >> 6;
  const int quad = lane >> 4, l15 = lane & 15;
  const int wm = (w & 1) * 32, wn = (w >> 1) * 32;
  const int sr = tid >> 2, sc = (tid & 3) * 8;
  const short* Ap = mid + ((size_t)e * 1024 + m0 + sr) * FF + sc;
  const short* Bp = wo_t + (size_t)e * DM * FF + (size_t)(n0 + sr) * FF + sc;
  GLOAD_LDS16(Ap, &As[0][tid * 8]);
  GLOAD_LDS16(Bp, &Bs[0][tid * 8]);
  __syncthreads();
  f32x4 acc[2][2];
#pragma unroll
  for (int i = 0; i < 2; ++i)
#pragma unroll
    for (int j = 0; j < 2; ++j) acc[i][j] = (f32x4){0.f, 0.f, 0.f, 0.f};
  for (int kt = 0; kt < FF; kt += 32) {
    const int cur = (kt >> 5) & 1;
    if (kt + 32 < FF) {
      const int nxt = cur ^ 1;
      GLOAD_LDS16(Ap + kt + 32, &As[nxt][tid * 8]);
      GLOAD_LDS16(Bp + kt + 32, &Bs[nxt][tid * 8]);
    }
    bf16x8 a[2], b[2];
#pragma unroll
    for (int i = 0; i < 2; ++i) {
      a[i] = *reinterpret_cast<const bf16x8*>(&As[cur][(wm + i * 16 + l15) * 32 + quad * 8]);
      b[i] = *reinterpret_cast<const bf16x8*>(&Bs[cur][(wn + i * 16 + l15) * 32 + quad * 8]);
    }
#pragma unroll
    for (int i = 0; i < 2; ++i)
#pragma unroll
      for (int j = 0; j < 2; ++j)
        acc[i][j] = __builtin_amdgcn_mfma_f32_16x16x32_bf16(a[i], b[j], acc[i][j], 0, 0, 0);
    __syncthreads();
  }
#pragma unroll
  for (int i = 0; i < 2; ++i) {
#pragma unroll
    for (int reg = 0; reg < 4; ++reg) {
      const int slot = m0 + wm + i * 16 + quad * 4 + reg;
      if (slot < tot) {
        const int idx = e * 1024 + slot;
        const int t = tok[idx];
        const float scv = mscale[idx];
        float* outr = moebuf + (size_t)t * DM + n0 + wn;
#pragma unroll
        for (int j = 0; j < 2; ++j) outr[j * 16 + l15] = scv * acc[i][j][reg];
      }
    }
  }
}

extern "C" void kernel_launch(void* const* d_in, const int* in_sizes, int n_in,
                              void* d_out, int out_size, void* d_ws, size_t ws_size,
                              hipStream_t stream) {
  const float* x     = (const float*)d_in[0];
  const float* in_w  = (const float*)d_in[1];
  const float* in_b  = (const float*)d_in[2];
  const float* out_w = (const float*)d_in[3];
  const float* out_b = (const float*)d_in[4];
  const float* ln1g  = (const float*)d_in[5];
  const float* ln1b  = (const float*)d_in[6];
  const float* ln2g  = (const float*)d_in[7];
  const float* ln2b  = (const float*)d_in[8];
  const float* rw    = (const float*)d_in[9];
  const float* wi    = (const float*)d_in[10];
  const float* wo    = (const float*)d_in[11];
  const int*   capp  = (const int*)d_in[12];

  float* ws = (float*)d_ws;
  short* qkh  = (short*)ws;                      // [0, 6291456) floats: qk/vt split planes
  short* qkl  = (short*)(ws + 2097152);
  short* vth  = (short*)(ws + 4194304);
  short* vtl  = (short*)(ws + 5242880);
  short* Gb16 = (short*)ws;                      // aliases qkh (post-attn)
  short* wi_t = (short*)(ws + 2097152);          // aliases qkl/vt (post-attn)
  float* moebuf = ws + 6291456;                  // 2,097,152
  float* r1     = ws + 8388608;                  // 2,097,152
  float* h      = ws + 10485760;                 // 2,097,152
  float* probs  = ws + 12582912;                 // 32,768
  short* wo_t   = (short*)(ws + 12615680);       // 8,388,608 shorts
  float* opart  = ws + 16809984;                 // 2 x 2,097,152 fp32 (aliases mid16, pre-FFN)
  float* mlbuf  = ws + 16809984 + 4194304;       // 131,072 fp32
  short* mid16  = (short*)(ws + 16809984);       // FFN phase
  float* mscale = ws + 25198592;
  int* am    = (int*)(ws + 25206784);
  int* pos   = am + NTOK;
  int* cnt   = pos + NTOK;
  int* tok   = cnt + 32;
  short* sAh = (short*)(ws + 25231360);          // 4096x512 shorts
  short* sAl = sAh + 2097152;
  short* sBh = sAl + 2097152;                    // 1536x512 shorts
  short* sBl = sBh + 786432;
  short* sCh = sBl + 786432;                     // 512x512 shorts
  short* sCl = sCh + 262144;

  float* out   = (float*)d_out;
  float* rlog  = out + 2097152;
  float* emask = rlog + 32768;

  // 1. fused split of x, in_proj_w, out_proj_w
  split3_kernel<<<1536, 256, 0, stream>>>(x, sAh, sAl, in_w, sBh, sBl, out_w, sCh, sCl);
  // 2. qkv GEMM -> split planes (BM=64 BN=64, dbuf, 1536 blocks)
  gemm_split_qkv<<<dim3(24, 64), 256, 0, stream>>>(sAh, sAl, sBh, sBl, in_b, qkh, qkl, vth, vtl);
  // 3. split-S MFMA attention (Q in regs, 32 KB LDS)
  attn_mfma<<<dim3(16, 8, 8), 256, 0, stream>>>(qkh, qkl, vth, vtl, opart, mlbuf);
  // 4. combine partials -> split attn_o planes (reuses sAh/sAl; x-split dead)
  combine_attn<<<NTOK, 64, 0, stream>>>(opart, mlbuf, sAh, sAl);
  // 5. r1 = attn_o @ out_w^T + out_b + x  (BM=64 BN=64, dbuf, 512 blocks)
  gemm_split_db<<<dim3(8, 64), 256, 0, stream>>>(sAh, sAl, sCh, sCl, out_b, x, r1, DM, DM);
  // 6. fused FFN weight transposes (overwrite qk/vt planes; attn done)
  transpose2_bf16<<<dim3(64, 16, 16), 256, 0, stream>>>(wi, wi_t, wo, wo_t);
  // 7. fused LN1 + router + softmax + argmax
  ln_router<<<NTOK, 64, 0, stream>>>(r1, ln1g, ln1b, rw, h, rlog, probs, am);
  // 8. capacity scan
  scan_kernel<<<32, 256, 0, stream>>>(am, probs, capp, emask, pos, cnt);
  // 9. gather kept tokens -> bf16
  gather_kernel<<<NTOK, 128, 0, stream>>>(h, am, pos, capp, cnt, probs, Gb16, tok, mscale);
  // 10-11. expert FFN (BM=64, dbuf)
  ffn1_mfma<<<dim3(16, 16, 8), 256, 0, stream>>>(Gb16, wi_t, mid16, cnt);
  ffn2_mfma<<<dim3(8, 16, 8), 256, 0, stream>>>(mid16, wo_t, tok, mscale, cnt, moebuf);
  // 12. out = LN2(h + kept?moebuf:0)
  ln2_kernel<<<NTOK, 64, 0, stream>>>(h, moebuf, pos, capp, ln2g, ln2b, out);
}

// Round 9
// 351.414 us; speedup vs baseline: 1.0019x; 1.0019x over previous
//
#include <hip/hip_runtime.h>
#include <math.h>

#define SEQ 1024
#define NTOK 4096
#define DM 512
#define FF 2048
#define NE 8

typedef __attribute__((ext_vector_type(8))) short bf16x8;
typedef __attribute__((ext_vector_type(4))) float f32x4;

__device__ __forceinline__ short f2bf(float f) {
  unsigned u = __float_as_uint(f);
  unsigned r = (u + 0x7FFFu + ((u >> 16) & 1u)) >> 16;
  return (short)r;
}
__device__ __forceinline__ float bf2f(short h) {
  return __uint_as_float(((unsigned)(unsigned short)h) << 16);
}

#define GLOAD_LDS16(g, l) __builtin_amdgcn_global_load_lds( \
    (const __attribute__((address_space(1))) void*)(g),     \
    (__attribute__((address_space(3))) void*)(l), 16, 0, 0)

// ---------- fused split of x, in_proj_w, out_proj_w -> (hi,lo) bf16 planes ----------
__global__ __launch_bounds__(256) void split3_kernel(
    const float* __restrict__ x, short* __restrict__ xh, short* __restrict__ xl,
    const float* __restrict__ w1, short* __restrict__ w1h, short* __restrict__ w1l,
    const float* __restrict__ w2, short* __restrict__ w2h, short* __restrict__ w2l) {
  const int bid = blockIdx.x;
  const float* src; short* hi; short* lo; size_t off;
  if (bid < 1024)      { src = x;  hi = xh;  lo = xl;  off = (size_t)bid * 2048; }
  else if (bid < 1408) { src = w1; hi = w1h; lo = w1l; off = (size_t)(bid - 1024) * 2048; }
  else                 { src = w2; hi = w2h; lo = w2l; off = (size_t)(bid - 1408) * 2048; }
  const size_t base = off + threadIdx.x * 8;
  float4 v0 = *reinterpret_cast<const float4*>(src + base);
  float4 v1 = *reinterpret_cast<const float4*>(src + base + 4);
  short h[8]; short l[8];
  float v[8] = {v0.x, v0.y, v0.z, v0.w, v1.x, v1.y, v1.z, v1.w};
#pragma unroll
  for (int i = 0; i < 8; ++i) {
    h[i] = f2bf(v[i]);
    l[i] = f2bf(v[i] - bf2f(h[i]));
  }
  *reinterpret_cast<short4*>(hi + base)     = make_short4(h[0], h[1], h[2], h[3]);
  *reinterpret_cast<short4*>(hi + base + 4) = make_short4(h[4], h[5], h[6], h[7]);
  *reinterpret_cast<short4*>(lo + base)     = make_short4(l[0], l[1], l[2], l[3]);
  *reinterpret_cast<short4*>(lo + base + 4) = make_short4(l[4], l[5], l[6], l[7]);
}

// ---------- split-bf16 MFMA GEMM, BM=64 BN=64, double-buffered staging ----------
// C = A@B^T + bias + resid
__global__ __launch_bounds__(256) void gemm_split_db(const short* __restrict__ Ah, const short* __restrict__ Al,
    const short* __restrict__ Bh, const short* __restrict__ Bl,
    const float* __restrict__ bias, const float* __restrict__ resid, float* __restrict__ C,
    int N, int K) {
  __shared__ __align__(16) short AsH[2][2048], AsL[2][2048], BsH[2][2048], BsL[2][2048];
  const int n0 = blockIdx.x * 64, m0 = blockIdx.y * 64;
  const int tid = threadIdx.x;
  const int lane = tid & 63, w = tid >> 6;
  const int quad = lane >> 4, l15 = lane & 15;
  const int wm = (w & 1) * 32, wn = (w >> 1) * 32;
  const int sr = tid >> 2, sc = (tid & 3) * 8;
  const short* Ahp = Ah + (size_t)(m0 + sr) * K + sc;
  const short* Alp = Al + (size_t)(m0 + sr) * K + sc;
  const short* Bhp = Bh + (size_t)(n0 + sr) * K + sc;
  const short* Blp = Bl + (size_t)(n0 + sr) * K + sc;
  GLOAD_LDS16(Ahp, &AsH[0][tid * 8]);
  GLOAD_LDS16(Alp, &AsL[0][tid * 8]);
  GLOAD_LDS16(Bhp, &BsH[0][tid * 8]);
  GLOAD_LDS16(Blp, &BsL[0][tid * 8]);
  __syncthreads();
  f32x4 acc[2][2];
#pragma unroll
  for (int i = 0; i < 2; ++i)
#pragma unroll
    for (int j = 0; j < 2; ++j) acc[i][j] = (f32x4){0.f, 0.f, 0.f, 0.f};
  for (int kt = 0; kt < K; kt += 32) {
    const int cur = (kt >> 5) & 1;
    if (kt + 32 < K) {
      const int nxt = cur ^ 1;
      GLOAD_LDS16(Ahp + kt + 32, &AsH[nxt][tid * 8]);
      GLOAD_LDS16(Alp + kt + 32, &AsL[nxt][tid * 8]);
      GLOAD_LDS16(Bhp + kt + 32, &BsH[nxt][tid * 8]);
      GLOAD_LDS16(Blp + kt + 32, &BsL[nxt][tid * 8]);
    }
    bf16x8 ah[2], al[2], bh[2], bl[2];
#pragma unroll
    for (int i = 0; i < 2; ++i) {
      ah[i] = *reinterpret_cast<const bf16x8*>(&AsH[cur][(wm + i * 16 + l15) * 32 + quad * 8]);
      al[i] = *reinterpret_cast<const bf16x8*>(&AsL[cur][(wm + i * 16 + l15) * 32 + quad * 8]);
      bh[i] = *reinterpret_cast<const bf16x8*>(&BsH[cur][(wn + i * 16 + l15) * 32 + quad * 8]);
      bl[i] = *reinterpret_cast<const bf16x8*>(&BsL[cur][(wn + i * 16 + l15) * 32 + quad * 8]);
    }
#pragma unroll
    for (int i = 0; i < 2; ++i)
#pragma unroll
      for (int j = 0; j < 2; ++j) {
        acc[i][j] = __builtin_amdgcn_mfma_f32_16x16x32_bf16(al[i], bh[j], acc[i][j], 0, 0, 0);
        acc[i][j] = __builtin_amdgcn_mfma_f32_16x16x32_bf16(ah[i], bl[j], acc[i][j], 0, 0, 0);
        acc[i][j] = __builtin_amdgcn_mfma_f32_16x16x32_bf16(ah[i], bh[j], acc[i][j], 0, 0, 0);
      }
    __syncthreads();
  }
#pragma unroll
  for (int i = 0; i < 2; ++i) {
#pragma unroll
    for (int reg = 0; reg < 4; ++reg) {
      const int row = m0 + wm + i * 16 + quad * 4 + reg;
#pragma unroll
      for (int j = 0; j < 2; ++j) {
        const int col = n0 + wn + j * 16 + l15;
        float v = acc[i][j][reg] + bias[col] + resid[(size_t)row * N + col];
        C[(size_t)row * N + col] = v;
      }
    }
  }
}

// ---------- qkv GEMM: BM=64 BN=64, double-buffered, epilogue emits split planes ----------
// K columns (512..1023) are pre-scaled by 0.125 (exact power-of-two -> softmax args bit-identical)
__global__ __launch_bounds__(256) void gemm_split_qkv(const short* __restrict__ Ah, const short* __restrict__ Al,
    const short* __restrict__ Bh, const short* __restrict__ Bl, const float* __restrict__ bias,
    short* __restrict__ qkh, short* __restrict__ qkl, short* __restrict__ vh, short* __restrict__ vl) {
  const int K = DM;
  __shared__ __align__(16) short AsH[2][2048], AsL[2][2048], BsH[2][2048], BsL[2][2048];
  const int n0 = blockIdx.x * 64, m0 = blockIdx.y * 64;
  const int tid = threadIdx.x;
  const int lane = tid & 63, w = tid >> 6;
  const int quad = lane >> 4, l15 = lane & 15;
  const int wm = (w & 1) * 32, wn = (w >> 1) * 32;
  const int sr = tid >> 2, sc = (tid & 3) * 8;
  const short* Ahp = Ah + (size_t)(m0 + sr) * K + sc;
  const short* Alp = Al + (size_t)(m0 + sr) * K + sc;
  const short* Bhp = Bh + (size_t)(n0 + sr) * K + sc;
  const short* Blp = Bl + (size_t)(n0 + sr) * K + sc;
  GLOAD_LDS16(Ahp, &AsH[0][tid * 8]);
  GLOAD_LDS16(Alp, &AsL[0][tid * 8]);
  GLOAD_LDS16(Bhp, &BsH[0][tid * 8]);
  GLOAD_LDS16(Blp, &BsL[0][tid * 8]);
  __syncthreads();
  f32x4 acc[2][2];
#pragma unroll
  for (int i = 0; i < 2; ++i)
#pragma unroll
    for (int j = 0; j < 2; ++j) acc[i][j] = (f32x4){0.f, 0.f, 0.f, 0.f};
  for (int kt = 0; kt < K; kt += 32) {
    const int cur = (kt >> 5) & 1;
    if (kt + 32 < K) {
      const int nxt = cur ^ 1;
      GLOAD_LDS16(Ahp + kt + 32, &AsH[nxt][tid * 8]);
      GLOAD_LDS16(Alp + kt + 32, &AsL[nxt][tid * 8]);
      GLOAD_LDS16(Bhp + kt + 32, &BsH[nxt][tid * 8]);
      GLOAD_LDS16(Blp + kt + 32, &BsL[nxt][tid * 8]);
    }
    bf16x8 ah[2], al[2], bh[2], bl[2];
#pragma unroll
    for (int i = 0; i < 2; ++i) {
      ah[i] = *reinterpret_cast<const bf16x8*>(&AsH[cur][(wm + i * 16 + l15) * 32 + quad * 8]);
      al[i] = *reinterpret_cast<const bf16x8*>(&AsL[cur][(wm + i * 16 + l15) * 32 + quad * 8]);
      bh[i] = *reinterpret_cast<const bf16x8*>(&BsH[cur][(wn + i * 16 + l15) * 32 + quad * 8]);
      bl[i] = *reinterpret_cast<const bf16x8*>(&BsL[cur][(wn + i * 16 + l15) * 32 + quad * 8]);
    }
#pragma unroll
    for (int i = 0; i < 2; ++i)
#pragma unroll
      for (int j = 0; j < 2; ++j) {
        acc[i][j] = __builtin_amdgcn_mfma_f32_16x16x32_bf16(al[i], bh[j], acc[i][j], 0, 0, 0);
        acc[i][j] = __builtin_amdgcn_mfma_f32_16x16x32_bf16(ah[i], bl[j], acc[i][j], 0, 0, 0);
        acc[i][j] = __builtin_amdgcn_mfma_f32_16x16x32_bf16(ah[i], bh[j], acc[i][j], 0, 0, 0);
      }
    __syncthreads();
  }
  if (n0 < 1024) {
    const float qs = (n0 >= 512) ? 0.125f : 1.0f;  // fold 1/sqrt(hd) into K (exact)
#pragma unroll
    for (int i = 0; i < 2; ++i) {
#pragma unroll
      for (int reg = 0; reg < 4; ++reg) {
        const int row = m0 + wm + i * 16 + quad * 4 + reg;
#pragma unroll
        for (int j = 0; j < 2; ++j) {
          const int col = n0 + wn + j * 16 + l15;
          float v = (acc[i][j][reg] + bias[col]) * qs;
          short hv = f2bf(v);
          size_t ad = (size_t)row * 1024 + col;
          qkh[ad] = hv;
          qkl[ad] = f2bf(v - bf2f(hv));
        }
      }
    }
  } else {
#pragma unroll
    for (int i = 0; i < 2; ++i) {
      const int row0 = m0 + wm + i * 16 + quad * 4;
      const int bb = row0 >> 10, s0 = row0 & 1023;
#pragma unroll
      for (int j = 0; j < 2; ++j) {
        const int col = n0 + wn + j * 16 + l15;
        const int c2 = col - 1024;
        const int hhd = c2 >> 6, d = c2 & 63;
        const float bc = bias[col];
        float v0 = acc[i][j][0] + bc, v1 = acc[i][j][1] + bc, v2 = acc[i][j][2] + bc, v3 = acc[i][j][3] + bc;
        short4 hv = make_short4(f2bf(v0), f2bf(v1), f2bf(v2), f2bf(v3));
        short4 lv = make_short4(f2bf(v0 - bf2f(hv.x)), f2bf(v1 - bf2f(hv.y)),
                                f2bf(v2 - bf2f(hv.z)), f2bf(v3 - bf2f(hv.w)));
        size_t ad = ((size_t)(bb * 8 + hhd) * 64 + d) * 1024 + s0;
        *reinterpret_cast<short4*>(vh + ad) = hv;
        *reinterpret_cast<short4*>(vl + ad) = lv;
      }
    }
  }
}

// ---------- MFMA flash attention: full KV per block, Q in regs, padded separate P ----------
// grid (16 qt, 8 h, 4 b). Emits normalized split-O planes directly (no combine pass).
#define PSTRIDE 72
__global__ __launch_bounds__(256) void attn_mfma(const short* __restrict__ qkh, const short* __restrict__ qkl,
    const short* __restrict__ vth, const short* __restrict__ vtl,
    short* __restrict__ oh, short* __restrict__ ol) {
  const int qt = blockIdx.x, hh = blockIdx.y, b = blockIdx.z;
  __shared__ __align__(16) short Kh[4096], Kl[4096], Vh[4096], Vl[4096];
  __shared__ __align__(16) short Ph[64 * PSTRIDE], Pl[64 * PSTRIDE];
  const int tid = threadIdx.x;
  const int lane = tid & 63, w = tid >> 6;
  const int quad = lane >> 4, l15 = lane & 15;
  const int tok0 = b * SEQ + qt * 64;
  const int srow = tid >> 2, schunk = (tid & 3) * 8;
  bf16x8 qfh[2], qfl[2];
  {
    const size_t qa = (size_t)(tok0 + w * 16 + l15) * 1024 + hh * 64 + quad * 8;
    qfh[0] = *reinterpret_cast<const bf16x8*>(qkh + qa);
    qfh[1] = *reinterpret_cast<const bf16x8*>(qkh + qa + 32);
    qfl[0] = *reinterpret_cast<const bf16x8*>(qkl + qa);
    qfl[1] = *reinterpret_cast<const bf16x8*>(qkl + qa + 32);
  }
  f32x4 oacc[4];
  float m_run[4], l_run[4];
#pragma unroll
  for (int r = 0; r < 4; ++r) { oacc[r] = (f32x4){0.f, 0.f, 0.f, 0.f}; m_run[r] = -1e30f; l_run[r] = 0.f; }
  const size_t kbase = (size_t)(b * SEQ) * 1024 + 512 + hh * 64;
  const size_t vbase = (size_t)(b * 8 + hh) * 64 * 1024;
  for (int kc = 0; kc < 16; ++kc) {
    const size_t ka = kbase + (size_t)(kc * 64 + srow) * 1024 + schunk;
    GLOAD_LDS16(qkh + ka,      &Kh[tid * 8]);
    GLOAD_LDS16(qkh + ka + 32, &Kh[2048 + tid * 8]);
    GLOAD_LDS16(qkl + ka,      &Kl[tid * 8]);
    GLOAD_LDS16(qkl + ka + 32, &Kl[2048 + tid * 8]);
    const size_t va = vbase + (size_t)srow * 1024 + kc * 64 + schunk;
    GLOAD_LDS16(vth + va,      &Vh[tid * 8]);
    GLOAD_LDS16(vth + va + 32, &Vh[2048 + tid * 8]);
    GLOAD_LDS16(vtl + va,      &Vl[tid * 8]);
    GLOAD_LDS16(vtl + va + 32, &Vl[2048 + tid * 8]);
    __syncthreads();
    // S = Q @ K^T (3-pass split); scores pre-scaled via K*0.125
    f32x4 s[4];
#pragma unroll
    for (int j = 0; j < 4; ++j) s[j] = (f32x4){0.f, 0.f, 0.f, 0.f};
#pragma unroll
    for (int kk = 0; kk < 2; ++kk)
#pragma unroll
      for (int j = 0; j < 4; ++j) {
        bf16x8 kfh = *reinterpret_cast<const bf16x8*>(&Kh[kk * 2048 + (j * 16 + l15) * 32 + quad * 8]);
        bf16x8 kfl = *reinterpret_cast<const bf16x8*>(&Kl[kk * 2048 + (j * 16 + l15) * 32 + quad * 8]);
        s[j] = __builtin_amdgcn_mfma_f32_16x16x32_bf16(qfl[kk], kfh, s[j], 0, 0, 0);
        s[j] = __builtin_amdgcn_mfma_f32_16x16x32_bf16(qfh[kk], kfl, s[j], 0, 0, 0);
        s[j] = __builtin_amdgcn_mfma_f32_16x16x32_bf16(qfh[kk], kfh, s[j], 0, 0, 0);
      }
    // online softmax (no barrier: P lives in its own buffer)
    float pv[4][4], alpha[4];
#pragma unroll
    for (int reg = 0; reg < 4; ++reg) {
      float mc = fmaxf(fmaxf(s[0][reg], s[1][reg]), fmaxf(s[2][reg], s[3][reg]));
#pragma unroll
      for (int msk = 1; msk < 16; msk <<= 1) mc = fmaxf(mc, __shfl_xor(mc, msk, 64));
      float mn = fmaxf(m_run[reg], mc);
      alpha[reg] = expf(m_run[reg] - mn);
      m_run[reg] = mn;
      float pl = 0.f;
#pragma unroll
      for (int j = 0; j < 4; ++j) { float pp = expf(s[j][reg] - mn); pv[j][reg] = pp; pl += pp; }
#pragma unroll
      for (int msk = 1; msk < 16; msk <<= 1) pl += __shfl_xor(pl, msk, 64);
      l_run[reg] = l_run[reg] * alpha[reg] + pl;
    }
#pragma unroll
    for (int j = 0; j < 4; ++j) {
      oacc[j][0] *= alpha[0]; oacc[j][1] *= alpha[1]; oacc[j][2] *= alpha[2]; oacc[j][3] *= alpha[3];
    }
    // write split P (padded stride; lo-plane truncated)
#pragma unroll
    for (int j = 0; j < 4; ++j) {
      const int cbase = j * 16 + l15;
#pragma unroll
      for (int reg = 0; reg < 4; ++reg) {
        const int ad = (w * 16 + quad * 4 + reg) * PSTRIDE + cbase;
        float p = pv[j][reg];
        short hp = f2bf(p);
        Ph[ad] = hp;
        Pl[ad] = (short)(__float_as_uint(p - bf2f(hp)) >> 16);
      }
    }
    // O += P @ V (3-pass split)
#pragma unroll
    for (int kk = 0; kk < 2; ++kk) {
      bf16x8 pfh = *reinterpret_cast<const bf16x8*>(&Ph[(w * 16 + l15) * PSTRIDE + kk * 32 + quad * 8]);
      bf16x8 pfl = *reinterpret_cast<const bf16x8*>(&Pl[(w * 16 + l15) * PSTRIDE + kk * 32 + quad * 8]);
#pragma unroll
      for (int j = 0; j < 4; ++j) {
        bf16x8 vfh = *reinterpret_cast<const bf16x8*>(&Vh[kk * 2048 + (j * 16 + l15) * 32 + quad * 8]);
        bf16x8 vfl = *reinterpret_cast<const bf16x8*>(&Vl[kk * 2048 + (j * 16 + l15) * 32 + quad * 8]);
        oacc[j] = __builtin_amdgcn_mfma_f32_16x16x32_bf16(pfl, vfh, oacc[j], 0, 0, 0);
        oacc[j] = __builtin_amdgcn_mfma_f32_16x16x32_bf16(pfh, vfl, oacc[j], 0, 0, 0);
        oacc[j] = __builtin_amdgcn_mfma_f32_16x16x32_bf16(pfh, vfh, oacc[j], 0, 0, 0);
      }
    }
    __syncthreads();  // K/V reads done before next-iter staging
  }
  // epilogue: normalize, emit split attn_o planes (consumed by out-proj GEMM)
#pragma unroll
  for (int reg = 0; reg < 4; ++reg) {
    const float inv = 1.f / l_run[reg];
#pragma unroll
    for (int j = 0; j < 4; ++j) {
      float v = oacc[j][reg] * inv;
      size_t ad = (size_t)(tok0 + w * 16 + quad * 4 + reg) * 512 + hh * 64 + j * 16 + l15;
      short hv = f2bf(v);
      oh[ad] = hv;
      ol[ad] = f2bf(v - bf2f(hv));
    }
  }
}

// ---------- fused LN1 + router logits + softmax + argmax ----------
__global__ __launch_bounds__(64) void ln_router(const float* __restrict__ r1,
    const float* __restrict__ g, const float* __restrict__ bta, const float* __restrict__ rw,
    float* __restrict__ h, float* __restrict__ rlog, float* __restrict__ probs, int* __restrict__ am) {
  const int t = blockIdx.x, tid = threadIdx.x;
  const size_t base = (size_t)t * DM + tid * 8;
  float4 v0 = *reinterpret_cast<const float4*>(r1 + base);
  float4 v1 = *reinterpret_cast<const float4*>(r1 + base + 4);
  float s = v0.x+v0.y+v0.z+v0.w + v1.x+v1.y+v1.z+v1.w;
  float q = v0.x*v0.x+v0.y*v0.y+v0.z*v0.z+v0.w*v0.w + v1.x*v1.x+v1.y*v1.y+v1.z*v1.z+v1.w*v1.w;
#pragma unroll
  for (int m = 1; m < 64; m <<= 1) { s += __shfl_xor(s, m, 64); q += __shfl_xor(q, m, 64); }
  float mean = s * (1.0f/512.0f);
  float var = q * (1.0f/512.0f) - mean * mean;
  float rs = rsqrtf(var + 1e-5f);
  float4 g0 = *reinterpret_cast<const float4*>(g + tid*8);
  float4 g1 = *reinterpret_cast<const float4*>(g + tid*8 + 4);
  float4 b0 = *reinterpret_cast<const float4*>(bta + tid*8);
  float4 b1 = *reinterpret_cast<const float4*>(bta + tid*8 + 4);
  float hv[8];
  hv[0] = (v0.x-mean)*rs*g0.x+b0.x; hv[1] = (v0.y-mean)*rs*g0.y+b0.y;
  hv[2] = (v0.z-mean)*rs*g0.z+b0.z; hv[3] = (v0.w-mean)*rs*g0.w+b0.w;
  hv[4] = (v1.x-mean)*rs*g1.x+b1.x; hv[5] = (v1.y-mean)*rs*g1.y+b1.y;
  hv[6] = (v1.z-mean)*rs*g1.z+b1.z; hv[7] = (v1.w-mean)*rs*g1.w+b1.w;
  *reinterpret_cast<float4*>(h + base)     = make_float4(hv[0], hv[1], hv[2], hv[3]);
  *reinterpret_cast<float4*>(h + base + 4) = make_float4(hv[4], hv[5], hv[6], hv[7]);
  float lg[8] = {0.f,0.f,0.f,0.f,0.f,0.f,0.f,0.f};
  const float* rwp = rw + tid * 64;
#pragma unroll
  for (int r = 0; r < 8; ++r) {
    float4 w0 = *reinterpret_cast<const float4*>(rwp + r * 8);
    float4 w1 = *reinterpret_cast<const float4*>(rwp + r * 8 + 4);
    float hr = hv[r];
    lg[0] += hr * w0.x; lg[1] += hr * w0.y; lg[2] += hr * w0.z; lg[3] += hr * w0.w;
    lg[4] += hr * w1.x; lg[5] += hr * w1.y; lg[6] += hr * w1.z; lg[7] += hr * w1.w;
  }
#pragma unroll
  for (int m = 1; m < 64; m <<= 1) {
#pragma unroll
    for (int e = 0; e < 8; ++e) lg[e] += __shfl_xor(lg[e], m, 64);
  }
  int best = 0; float bv = lg[0];
#pragma unroll
  for (int e = 1; e < 8; ++e) if (lg[e] > bv) { bv = lg[e]; best = e; }
  float se = 0.f;
#pragma unroll
  for (int e = 0; e < 8; ++e) se += expf(lg[e] - bv);
  float inv = 1.f / se;
  if (tid < 8) {
    rlog[t * 8 + tid] = lg[tid];
    probs[t * 8 + tid] = expf(lg[tid] - bv) * inv;
  }
  if (tid == 0) am[t] = best;
}

// LN2 with capacity-guarded MoE add
__global__ __launch_bounds__(64) void ln2_kernel(const float* __restrict__ x, const float* __restrict__ add,
    const int* __restrict__ pos, const int* __restrict__ capp,
    const float* __restrict__ g, const float* __restrict__ bta, float* __restrict__ y) {
  const int t = blockIdx.x, tid = threadIdx.x;
  const size_t base = (size_t)t * DM + tid * 8;
  float4 v0 = *reinterpret_cast<const float4*>(x + base);
  float4 v1 = *reinterpret_cast<const float4*>(x + base + 4);
  if (pos[t] <= *capp) {
    float4 a0 = *reinterpret_cast<const float4*>(add + base);
    float4 a1 = *reinterpret_cast<const float4*>(add + base + 4);
    v0.x += a0.x; v0.y += a0.y; v0.z += a0.z; v0.w += a0.w;
    v1.x += a1.x; v1.y += a1.y; v1.z += a1.z; v1.w += a1.w;
  }
  float s = v0.x+v0.y+v0.z+v0.w + v1.x+v1.y+v1.z+v1.w;
  float q = v0.x*v0.x+v0.y*v0.y+v0.z*v0.z+v0.w*v0.w + v1.x*v1.x+v1.y*v1.y+v1.z*v1.z+v1.w*v1.w;
#pragma unroll
  for (int m = 1; m < 64; m <<= 1) { s += __shfl_xor(s, m, 64); q += __shfl_xor(q, m, 64); }
  float mean = s * (1.0f/512.0f);
  float var = q * (1.0f/512.0f) - mean * mean;
  float rs = rsqrtf(var + 1e-5f);
  float4 g0 = *reinterpret_cast<const float4*>(g + tid*8);
  float4 g1 = *reinterpret_cast<const float4*>(g + tid*8 + 4);
  float4 b0 = *reinterpret_cast<const float4*>(bta + tid*8);
  float4 b1 = *reinterpret_cast<const float4*>(bta + tid*8 + 4);
  float4 o0 = make_float4((v0.x-mean)*rs*g0.x+b0.x, (v0.y-mean)*rs*g0.y+b0.y,
                          (v0.z-mean)*rs*g0.z+b0.z, (v0.w-mean)*rs*g0.w+b0.w);
  float4 o1 = make_float4((v1.x-mean)*rs*g1.x+b1.x, (v1.y-mean)*rs*g1.y+b1.y,
                          (v1.z-mean)*rs*g1.z+b1.z, (v1.w-mean)*rs*g1.w+b1.w);
  *reinterpret_cast<float4*>(y + base) = o0;
  *reinterpret_cast<float4*>(y + base + 4) = o1;
}

__global__ __launch_bounds__(256) void scan_kernel(const int* __restrict__ am, const float* __restrict__ probs,
    const int* __restrict__ capp, float* __restrict__ emask, int* __restrict__ pos, int* __restrict__ cnt) {
  const int bx = blockIdx.x;
  const int b = bx >> 3, e = bx & 7;
  const int tid = threadIdx.x;
  const int cap = *capp;
  __shared__ int arr[256];
  const int s_base = tid * 4;
  int f[4], incl[4];
  int c = 0;
#pragma unroll
  for (int i = 0; i < 4; ++i) {
    f[i] = (am[b * SEQ + s_base + i] == e) ? 1 : 0;
    c += f[i]; incl[i] = c;
  }
  arr[tid] = c;
  __syncthreads();
  for (int off = 1; off < 256; off <<= 1) {
    int v = (tid >= off) ? arr[tid - off] : 0;
    __syncthreads();
    arr[tid] += v;
    __syncthreads();
  }
  int excl = arr[tid] - c;
  int tot = arr[255];
#pragma unroll
  for (int i = 0; i < 4; ++i) {
    int token = b * SEQ + s_base + i;
    int p = excl + incl[i];
    bool kept = f[i] && (p <= cap);
    emask[(size_t)token * NE + e] = kept ? probs[token * NE + e] : 0.f;
    if (f[i]) pos[token] = p;
  }
  if (tid == 0) cnt[bx] = (tot < cap) ? tot : cap;
}

// ---------- fused weight transpose (wi + wo) ----------
__global__ __launch_bounds__(256) void transpose2_bf16(const float* __restrict__ wi, short* __restrict__ wi_t,
    const float* __restrict__ wo, short* __restrict__ wo_t) {
  __shared__ float T[32][33];
  const int z = blockIdx.z;
  const float* W; short* Wt; int K, N, k0, n0;
  if (z < 8) { W = wi + (size_t)z * DM * FF;      Wt = wi_t + (size_t)z * DM * FF;
               K = DM; N = FF; k0 = blockIdx.y * 32; n0 = blockIdx.x * 32; }
  else       { W = wo + (size_t)(z - 8) * FF * DM; Wt = wo_t + (size_t)(z - 8) * FF * DM;
               K = FF; N = DM; k0 = blockIdx.x * 32; n0 = blockIdx.y * 32; }
  const int r = threadIdx.x >> 3, c4 = (threadIdx.x & 7) * 4;
  float4 v = *reinterpret_cast<const float4*>(&W[(size_t)(k0 + r) * N + n0 + c4]);
  T[r][c4+0] = v.x; T[r][c4+1] = v.y; T[r][c4+2] = v.z; T[r][c4+3] = v.w;
  __syncthreads();
  short4 o;
  o.x = f2bf(T[c4+0][r]); o.y = f2bf(T[c4+1][r]); o.z = f2bf(T[c4+2][r]); o.w = f2bf(T[c4+3][r]);
  *reinterpret_cast<short4*>(&Wt[(size_t)(n0 + r) * K + k0 + c4]) = o;
}

// gather kept tokens (computes per-(b,e) offset from cnt inline)
__global__ __launch_bounds__(128) void gather_kernel(const float* __restrict__ h, const int* __restrict__ am,
    const int* __restrict__ pos, const int* __restrict__ capp, const int* __restrict__ cnt,
    const float* __restrict__ probs, short* __restrict__ Gb, int* __restrict__ tok, float* __restrict__ mscale) {
  const int t = blockIdx.x;
  const int b = t >> 10;
  const int e = am[t];
  const int p = pos[t];
  if (p > *capp) return;
  int off = 0;
  for (int b2 = 0; b2 < b; ++b2) off += cnt[b2 * 8 + e];
  const int slot = off + p - 1;
  const int idx = e * 1024 + slot;
  if (threadIdx.x == 0) { tok[idx] = t; mscale[idx] = probs[t * NE + e]; }
  float4 v = *reinterpret_cast<const float4*>(h + (size_t)t * DM + threadIdx.x * 4);
  short4 o; o.x = f2bf(v.x); o.y = f2bf(v.y); o.z = f2bf(v.z); o.w = f2bf(v.w);
  *reinterpret_cast<short4*>(Gb + (size_t)idx * DM + threadIdx.x * 4) = o;
}

// ---------- ffn1: BM=64 BN=128, double-buffered. 4 waves split N. ----------
__global__ __launch_bounds__(256) void ffn1_mfma(const short* __restrict__ Gb, const short* __restrict__ wi_t,
    short* __restrict__ mid, const int* __restrict__ cnt) {
  const int e = blockIdx.z;
  const int tot = cnt[e] + cnt[8 + e] + cnt[16 + e] + cnt[24 + e];
  const int m0 = blockIdx.y * 64;
  if (m0 >= tot) return;
  const int n0 = blockIdx.x * 128;
  __shared__ __align__(16) short As[2][2048];
  __shared__ __align__(16) short Bs[2][4096];
  const int tid = threadIdx.x;
  const int lane = tid & 63, w = tid >> 6;
  const int quad = lane >> 4, l15 = lane & 15;
  const int wn = w * 32;
  const int sr = tid >> 2, sc = (tid & 3) * 8;
  const short* Ap  = Gb + ((size_t)e * 1024 + m0 + sr) * DM + sc;
  const short* Bp  = wi_t + (size_t)e * FF * DM + (size_t)(n0 + sr) * DM + sc;
  const short* Bp2 = wi_t + (size_t)e * FF * DM + (size_t)(n0 + 64 + sr) * DM + sc;
  GLOAD_LDS16(Ap,  &As[0][tid * 8]);
  GLOAD_LDS16(Bp,  &Bs[0][tid * 8]);
  GLOAD_LDS16(Bp2, &Bs[0][2048 + tid * 8]);
  __syncthreads();
  f32x4 acc[4][2];
#pragma unroll
  for (int i = 0; i < 4; ++i)
#pragma unroll
    for (int j = 0; j < 2; ++j) acc[i][j] = (f32x4){0.f, 0.f, 0.f, 0.f};
  for (int kt = 0; kt < DM; kt += 32) {
    const int cur = (kt >> 5) & 1;
    if (kt + 32 < DM) {
      const int nxt = cur ^ 1;
      GLOAD_LDS16(Ap + kt + 32,  &As[nxt][tid * 8]);
      GLOAD_LDS16(Bp + kt + 32,  &Bs[nxt][tid * 8]);
      GLOAD_LDS16(Bp2 + kt + 32, &Bs[nxt][2048 + tid * 8]);
    }
    bf16x8 a[4], b[2];
#pragma unroll
    for (int i = 0; i < 4; ++i) a[i] = *reinterpret_cast<const bf16x8*>(&As[cur][(i * 16 + l15) * 32 + quad * 8]);
#pragma unroll
    for (int j = 0; j < 2; ++j) b[j] = *reinterpret_cast<const bf16x8*>(&Bs[cur][(wn + j * 16 + l15) * 32 + quad * 8]);
#pragma unroll
    for (int i = 0; i < 4; ++i)
#pragma unroll
      for (int j = 0; j < 2; ++j)
        acc[i][j] = __builtin_amdgcn_mfma_f32_16x16x32_bf16(a[i], b[j], acc[i][j], 0, 0, 0);
    __syncthreads();
  }
#pragma unroll
  for (int i = 0; i < 4; ++i) {
#pragma unroll
    for (int reg = 0; reg < 4; ++reg) {
      const int row = m0 + i * 16 + quad * 4 + reg;
      short* outr = mid + ((size_t)e * 1024 + row) * FF;
#pragma unroll
      for (int j = 0; j < 2; ++j) {
        float v = acc[i][j][reg];
        float gl = 0.5f * v * (1.f + erff(v * 0.70710678118654752f));
        outr[n0 + wn + j * 16 + l15] = f2bf(gl);
      }
    }
  }
}

// ---------- ffn2: BM=64 BN=64, double-buffered. ----------
__global__ __launch_bounds__(256) void ffn2_mfma(const short* __restrict__ mid, const short* __restrict__ wo_t,
    const int* __restrict__ tok, const float* __restrict__ mscale, const int* __restrict__ cnt,
    float* __restrict__ moebuf) {
  const int e = blockIdx.z;
  const int tot = cnt[e] + cnt[8 + e] + cnt[16 + e] + cnt[24 + e];
  const int m0 = blockIdx.y * 64;
  if (m0 >= tot) return;
  const int n0 = blockIdx.x * 64;
  __shared__ __align__(16) short As[2][2048];
  __shared__ __align__(16) short Bs[2][2048];
  const int tid = threadIdx.x;
  const int lane = tid & 63, w = tid >> 6;
  const int quad = lane >> 4, l15 = lane & 15;
  const int wm = (w & 1) * 32, wn = (w >> 1) * 32;
  const int sr = tid >> 2, sc = (tid & 3) * 8;
  const short* Ap = mid + ((size_t)e * 1024 + m0 + sr) * FF + sc;
  const short* Bp = wo_t + (size_t)e * DM * FF + (size_t)(n0 + sr) * FF + sc;
  GLOAD_LDS16(Ap, &As[0][tid * 8]);
  GLOAD_LDS16(Bp, &Bs[0][tid * 8]);
  __syncthreads();
  f32x4 acc[2][2];
#pragma unroll
  for (int i = 0; i < 2; ++i)
#pragma unroll
    for (int j = 0; j < 2; ++j) acc[i][j] = (f32x4){0.f, 0.f, 0.f, 0.f};
  for (int kt = 0; kt < FF; kt += 32) {
    const int cur = (kt >> 5) & 1;
    if (kt + 32 < FF) {
      const int nxt = cur ^ 1;
      GLOAD_LDS16(Ap + kt + 32, &As[nxt][tid * 8]);
      GLOAD_LDS16(Bp + kt + 32, &Bs[nxt][tid * 8]);
    }
    bf16x8 a[2], b[2];
#pragma unroll
    for (int i = 0; i < 2; ++i) {
      a[i] = *reinterpret_cast<const bf16x8*>(&As[cur][(wm + i * 16 + l15) * 32 + quad * 8]);
      b[i] = *reinterpret_cast<const bf16x8*>(&Bs[cur][(wn + i * 16 + l15) * 32 + quad * 8]);
    }
#pragma unroll
    for (int i = 0; i < 2; ++i)
#pragma unroll
      for (int j = 0; j < 2; ++j)
        acc[i][j] = __builtin_amdgcn_mfma_f32_16x16x32_bf16(a[i], b[j], acc[i][j], 0, 0, 0);
    __syncthreads();
  }
#pragma unroll
  for (int i = 0; i < 2; ++i) {
#pragma unroll
    for (int reg = 0; reg < 4; ++reg) {
      const int slot = m0 + wm + i * 16 + quad * 4 + reg;
      if (slot < tot) {
        const int idx = e * 1024 + slot;
        const int t = tok[idx];
        const float scv = mscale[idx];
        float* outr = moebuf + (size_t)t * DM + n0 + wn;
#pragma unroll
        for (int j = 0; j < 2; ++j) outr[j * 16 + l15] = scv * acc[i][j][reg];
      }
    }
  }
}

extern "C" void kernel_launch(void* const* d_in, const int* in_sizes, int n_in,
                              void* d_out, int out_size, void* d_ws, size_t ws_size,
                              hipStream_t stream) {
  const float* x     = (const float*)d_in[0];
  const float* in_w  = (const float*)d_in[1];
  const float* in_b  = (const float*)d_in[2];
  const float* out_w = (const float*)d_in[3];
  const float* out_b = (const float*)d_in[4];
  const float* ln1g  = (const float*)d_in[5];
  const float* ln1b  = (const float*)d_in[6];
  const float* ln2g  = (const float*)d_in[7];
  const float* ln2b  = (const float*)d_in[8];
  const float* rw    = (const float*)d_in[9];
  const float* wi    = (const float*)d_in[10];
  const float* wo    = (const float*)d_in[11];
  const int*   capp  = (const int*)d_in[12];

  float* ws = (float*)d_ws;
  short* qkh  = (short*)ws;                      // [0, 6291456) floats: qk/vt split planes
  short* qkl  = (short*)(ws + 2097152);
  short* vth  = (short*)(ws + 4194304);
  short* vtl  = (short*)(ws + 5242880);
  short* Gb16 = (short*)ws;                      // aliases qkh (post-attn)
  short* wi_t = (short*)(ws + 2097152);          // aliases qkl/vt (post-attn)
  float* moebuf = ws + 6291456;                  // 2,097,152
  float* r1     = ws + 8388608;                  // 2,097,152
  float* h      = ws + 10485760;                 // 2,097,152
  float* probs  = ws + 12582912;                 // 32,768
  short* wo_t   = (short*)(ws + 12615680);       // 8,388,608 shorts
  short* mid16  = (short*)(ws + 16809984);       // 16,777,216 shorts (FFN phase)
  float* mscale = ws + 25198592;
  int* am    = (int*)(ws + 25206784);
  int* pos   = am + NTOK;
  int* cnt   = pos + NTOK;
  int* tok   = cnt + 32;
  short* sAh = (short*)(ws + 25231360);          // 4096x512 shorts (x-split, then attn_o split)
  short* sAl = sAh + 2097152;
  short* sBh = sAl + 2097152;                    // 1536x512 shorts
  short* sBl = sBh + 786432;
  short* sCh = sBl + 786432;                     // 512x512 shorts
  short* sCl = sCh + 262144;

  float* out   = (float*)d_out;
  float* rlog  = out + 2097152;
  float* emask = rlog + 32768;

  // 1. fused split of x, in_proj_w, out_proj_w
  split3_kernel<<<1536, 256, 0, stream>>>(x, sAh, sAl, in_w, sBh, sBl, out_w, sCh, sCl);
  // 2. qkv GEMM -> split planes (K pre-scaled by 0.125)
  gemm_split_qkv<<<dim3(24, 64), 256, 0, stream>>>(sAh, sAl, sBh, sBl, in_b, qkh, qkl, vth, vtl);
  // 3. MFMA attention (full KV per block) -> split attn_o planes into sAh/sAl (x-split dead)
  attn_mfma<<<dim3(16, 8, 4), 256, 0, stream>>>(qkh, qkl, vth, vtl, sAh, sAl);
  // 4. r1 = attn_o @ out_w^T + out_b + x
  gemm_split_db<<<dim3(8, 64), 256, 0, stream>>>(sAh, sAl, sCh, sCl, out_b, x, r1, DM, DM);
  // 5. fused FFN weight transposes (overwrite qk/vt planes; attn done)
  transpose2_bf16<<<dim3(64, 16, 16), 256, 0, stream>>>(wi, wi_t, wo, wo_t);
  // 6. fused LN1 + router + softmax + argmax
  ln_router<<<NTOK, 64, 0, stream>>>(r1, ln1g, ln1b, rw, h, rlog, probs, am);
  // 7. capacity scan
  scan_kernel<<<32, 256, 0, stream>>>(am, probs, capp, emask, pos, cnt);
  // 8. gather kept tokens -> bf16
  gather_kernel<<<NTOK, 128, 0, stream>>>(h, am, pos, capp, cnt, probs, Gb16, tok, mscale);
  // 9-10. expert FFN
  ffn1_mfma<<<dim3(16, 16, 8), 256, 0, stream>>>(Gb16, wi_t, mid16, cnt);
  ffn2_mfma<<<dim3(8, 16, 8), 256, 0, stream>>>(mid16, wo_t, tok, mscale, cnt, moebuf);
  // 11. out = LN2(h + kept?moebuf:0)
  ln2_kernel<<<NTOK, 64, 0, stream>>>(h, moebuf, pos, capp, ln2g, ln2b, out);
}